// Round 1
// baseline (567.863 us; speedup 1.0000x reference)
//
#include <hip/hip_runtime.h>

#define M_DIM 3072
#define N_DIM 3072
#define MN (M_DIM * N_DIM)        // 9437184, divisible by 4
#define NVEC (MN / 4)             // 2359296 float4 per channel plane

__global__ __launch_bounds__(256) void hist_kernel(
    const float4* __restrict__ x,   // (10, MN/4) float4 planes
    float4* __restrict__ out)       // (8,  MN/4) float4 planes
{
    int i = blockIdx.x * blockDim.x + threadIdx.x;
    if (i >= NVEC) return;

    // Load 8 cosine channels (each plane contiguous, stride NVEC float4s).
    float c[8][4];
#pragma unroll
    for (int ch = 0; ch < 8; ++ch) {
        float4 v = x[(size_t)ch * NVEC + i];
        c[ch][0] = v.x; c[ch][1] = v.y; c[ch][2] = v.z; c[ch][3] = v.w;
    }

    // Gradients -> magnitude per element.
    float4 ga = x[(size_t)8 * NVEC + i];
    float4 gb = x[(size_t)9 * NVEC + i];
    float mag[4];
    mag[0] = sqrtf(ga.x * ga.x + gb.x * gb.x);
    mag[1] = sqrtf(ga.y * ga.y + gb.y * gb.y);
    mag[2] = sqrtf(ga.z * ga.z + gb.z * gb.z);
    mag[3] = sqrtf(ga.w * ga.w + gb.w * gb.w);

    // Argmax over 8 channels, first-index tie-break (strict >), per element.
    int   best[4];
    float bv[4];
#pragma unroll
    for (int e = 0; e < 4; ++e) { best[e] = 0; bv[e] = c[0][e]; }
#pragma unroll
    for (int ch = 1; ch < 8; ++ch) {
#pragma unroll
        for (int e = 0; e < 4; ++e) {
            if (c[ch][e] > bv[e]) { bv[e] = c[ch][e]; best[e] = ch; }
        }
    }

    // Write 8 output channels: mag on argmax channel, 0 elsewhere.
#pragma unroll
    for (int ch = 0; ch < 8; ++ch) {
        float4 o;
        o.x = (best[0] == ch) ? mag[0] : 0.0f;
        o.y = (best[1] == ch) ? mag[1] : 0.0f;
        o.z = (best[2] == ch) ? mag[2] : 0.0f;
        o.w = (best[3] == ch) ? mag[3] : 0.0f;
        out[(size_t)ch * NVEC + i] = o;
    }
}

extern "C" void kernel_launch(void* const* d_in, const int* in_sizes, int n_in,
                              void* d_out, int out_size, void* d_ws, size_t ws_size,
                              hipStream_t stream) {
    const float4* x = (const float4*)d_in[0];
    float4* out = (float4*)d_out;
    int blocks = (NVEC + 255) / 256;   // 9216 blocks, exact
    hist_kernel<<<blocks, 256, 0, stream>>>(x, out);
}